// Round 7
// baseline (524.847 us; speedup 1.0000x reference)
//
#include <hip/hip_runtime.h>

#define BATCH 32
#define DIM 4096
#define NH 32
#define NKV 8
#define HD 128
#define CTX 4096
#define NEWT 4095
#define CHUNK 512
#define NCH 8
#define NSPLIT 32
#define KCH (DIM / NSPLIT)   // 128
#define NQKV 6144            // 4096 q + 1024 k + 1024 v
#define SM_SCALE 0.08838834764831845f  // 1/sqrt(128)

// ---- stage 1: partial GEMM, no atomics ----
__global__ __launch_bounds__(256) void gemm_qkv_part(
    const float* __restrict__ A, const float* __restrict__ wq,
    const float* __restrict__ wk, const float* __restrict__ wv,
    float* __restrict__ part) {
  int bx = blockIdx.x;
  int sy = blockIdx.y;
  int cg = bx * 256 + threadIdx.x;
  const float* W; int cw, Nw;
  if (bx < 16)      { W = wq; cw = cg;        Nw = 4096; }
  else if (bx < 20) { W = wk; cw = cg - 4096; Nw = 1024; }
  else              { W = wv; cw = cg - 5120; Nw = 1024; }
  int k0 = sy * KCH;
  float acc[BATCH];
#pragma unroll
  for (int b = 0; b < BATCH; ++b) acc[b] = 0.f;
  const float* Wp = W + (size_t)k0 * Nw + cw;
  const float* Ap = A + k0;
#pragma unroll 4
  for (int k = 0; k < KCH; ++k) {
    float wval = Wp[(size_t)k * Nw];
#pragma unroll
    for (int b = 0; b < BATCH; ++b)
      acc[b] += Ap[b * DIM + k] * wval;
  }
#pragma unroll
  for (int b = 0; b < BATCH; ++b)
    part[((size_t)sy * BATCH + b) * NQKV + cg] = acc[b];
}

// ---- stage 2: reduce partials + RoPE ----
__global__ __launch_bounds__(256) void qkv_reduce_rope(
    const float* __restrict__ part, const float* __restrict__ cos_t,
    const float* __restrict__ sin_t, float* __restrict__ q,
    float* __restrict__ k, float* __restrict__ v) {
  int idx = blockIdx.x * 256 + threadIdx.x;
  int b = idx / 3072, c2 = idx - b * 3072;
  int c = c2 * 2;
  float s0 = 0.f, s1 = 0.f;
#pragma unroll 8
  for (int s = 0; s < NSPLIT; ++s) {
    float2 pv = *(const float2*)&part[((size_t)s * BATCH + b) * NQKV + c];
    s0 += pv.x; s1 += pv.y;
  }
  if (c < 4096) {
    int p = (c & 127) >> 1;
    float cc = cos_t[p], ss = sin_t[p];
    q[b * 4096 + c]     = s0 * cc - s1 * ss;
    q[b * 4096 + c + 1] = s0 * ss + s1 * cc;
  } else if (c < 5120) {
    int c0 = c - 4096;
    int p = (c0 & 127) >> 1;
    float cc = cos_t[p], ss = sin_t[p];
    k[b * 1024 + c0]     = s0 * cc - s1 * ss;
    k[b * 1024 + c0 + 1] = s0 * ss + s1 * cc;
  } else {
    int c0 = c - 5120;
    v[b * 1024 + c0]     = s0;
    v[b * 1024 + c0 + 1] = s1;
  }
}

// ---- flash-decode partial: one block per (b, kv_head, chunk) ----
__global__ __launch_bounds__(256, 2) void attn_kernel(
    const float* __restrict__ q,
    const float* __restrict__ kcache,
    const float* __restrict__ vcache,
    const float* __restrict__ knew,
    const float* __restrict__ vnew,
    float* __restrict__ pm, float* __restrict__ pl,
    float* __restrict__ pacc) {
  __shared__ float sc[4 * CHUNK];   // 8 KB
  __shared__ float sml[8];
  int blk = blockIdx.x;
  int c = blk & 7, h = (blk >> 3) & 7, b = blk >> 6;
  int tid = threadIdx.x;
  int wave = tid >> 6, sub = tid & 63;
  int t_base = c * CHUNK;

  // phase 1: scores
  int tg = tid >> 4;    // 0..15 t-rows per pass
  int lig = tid & 15;   // covers 8 d's
  float qreg[4][8];
#pragma unroll
  for (int r = 0; r < 4; ++r)
#pragma unroll
    for (int j = 0; j < 8; ++j)
      qreg[r][j] = q[b * (NH * HD) + (h * 4 + r) * HD + lig * 8 + j];

  const float* kbase = kcache + ((size_t)b * CTX * NKV + h) * HD;
  const float* knrow = knew + (b * NKV + h) * HD;
  for (int t0 = 0; t0 < CHUNK; t0 += 16) {
    int tl = t0 + tg;
    int t = t_base + tl;
    const float* krow = (t < NEWT) ? (kbase + (size_t)t * (NKV * HD)) : knrow;
    float4 ka = *(const float4*)(krow + lig * 8);
    float4 kb = *(const float4*)(krow + lig * 8 + 4);
#pragma unroll
    for (int r = 0; r < 4; ++r) {
      float part = ka.x * qreg[r][0] + ka.y * qreg[r][1] + ka.z * qreg[r][2] + ka.w * qreg[r][3]
                 + kb.x * qreg[r][4] + kb.y * qreg[r][5] + kb.z * qreg[r][6] + kb.w * qreg[r][7];
#pragma unroll
      for (int off = 8; off >= 1; off >>= 1)
        part += __shfl_xor(part, off);
      if (lig == 0) sc[r * CHUNK + tl] = part * SM_SCALE;
    }
  }
  __syncthreads();

  // chunk softmax (unnormalized), wave r handles row r
  {
    int r = wave;
    float m = -1e30f;
    for (int i = sub; i < CHUNK; i += 64) m = fmaxf(m, sc[r * CHUNK + i]);
#pragma unroll
    for (int off = 32; off >= 1; off >>= 1) m = fmaxf(m, __shfl_xor(m, off));
    float ssum = 0.f;
    for (int i = sub; i < CHUNK; i += 64) {
      float pv = __expf(sc[r * CHUNK + i] - m);
      sc[r * CHUNK + i] = pv;
      ssum += pv;
    }
#pragma unroll
    for (int off = 32; off >= 1; off >>= 1) ssum += __shfl_xor(ssum, off);
    if (sub == 0) { sml[r] = m; sml[4 + r] = ssum; }
  }
  __syncthreads();
  if (tid < 4) {
    pm[blk * 4 + tid] = sml[tid];
    pl[blk * 4 + tid] = sml[4 + tid];
  }

  // phase 2: acc[r][d] = sum_t p[r][t] * V[t][d]
  int dg = tid & 31;
  int tg2 = tid >> 5;   // 0..7
  float4 acc[4];
#pragma unroll
  for (int r = 0; r < 4; ++r) acc[r] = make_float4(0.f, 0.f, 0.f, 0.f);
  const float* vbase = vcache + ((size_t)b * CTX * NKV + h) * HD;
  const float* vnrow = vnew + (b * NKV + h) * HD;
  for (int t0 = 0; t0 < CHUNK; t0 += 16) {
    int tla = t0 + tg2, tlb = t0 + tg2 + 8;
    int ta = t_base + tla, tb = t_base + tlb;
    const float* vra = (ta < NEWT) ? (vbase + (size_t)ta * (NKV * HD)) : vnrow;
    const float* vrb = (tb < NEWT) ? (vbase + (size_t)tb * (NKV * HD)) : vnrow;
    float4 va = *(const float4*)(vra + dg * 4);
    float4 vb = *(const float4*)(vrb + dg * 4);
#pragma unroll
    for (int r = 0; r < 4; ++r) {
      float pa = sc[r * CHUNK + tla];
      float pb = sc[r * CHUNK + tlb];
      acc[r].x += pa * va.x + pb * vb.x;
      acc[r].y += pa * va.y + pb * vb.y;
      acc[r].z += pa * va.z + pb * vb.z;
      acc[r].w += pa * va.w + pb * vb.w;
    }
  }
#pragma unroll
  for (int r = 0; r < 4; ++r) {
    acc[r].x += __shfl_xor(acc[r].x, 32);
    acc[r].y += __shfl_xor(acc[r].y, 32);
    acc[r].z += __shfl_xor(acc[r].z, 32);
    acc[r].w += __shfl_xor(acc[r].w, 32);
  }
  __syncthreads();
  if (sub < 32) {
#pragma unroll
    for (int r = 0; r < 4; ++r)
      *(float4*)&sc[wave * 512 + r * 128 + dg * 4] = acc[r];
  }
  __syncthreads();
#pragma unroll
  for (int rr = 0; rr < 2; ++rr) {
    int idx = tid + rr * 256;
    int r = idx >> 7, d = idx & 127;
    float s = sc[r * 128 + d] + sc[512 + r * 128 + d]
            + sc[1024 + r * 128 + d] + sc[1536 + r * 128 + d];
    pacc[(size_t)blk * 512 + r * 128 + d] = s;
  }
}

__global__ __launch_bounds__(256) void combine_kernel(
    const float* __restrict__ pm, const float* __restrict__ pl,
    const float* __restrict__ pacc, float* __restrict__ outa) {
  int idx = blockIdx.x * 256 + threadIdx.x;
  int d = idx & 127, r = (idx >> 7) & 3, h = (idx >> 9) & 7, b = idx >> 12;
  int base = (b * 8 + h) * 8;
  float M = -1e30f;
#pragma unroll
  for (int c = 0; c < NCH; ++c) M = fmaxf(M, pm[(base + c) * 4 + r]);
  float num = 0.f, den = 0.f;
#pragma unroll
  for (int c = 0; c < NCH; ++c) {
    float w = __expf(pm[(base + c) * 4 + r] - M);
    den += w * pl[(base + c) * 4 + r];
    num += w * pacc[(size_t)(base + c) * 512 + r * 128 + d];
  }
  outa[b * (NH * HD) + (h * 4 + r) * HD + d] = num / den;
}

// ---- wo projection ----
__global__ __launch_bounds__(256) void gemm_wo_part(
    const float* __restrict__ A, const float* __restrict__ W,
    float* __restrict__ part) {
  int c = blockIdx.x * 256 + threadIdx.x;
  int sy = blockIdx.y;
  int k0 = sy * KCH;
  float acc[BATCH];
#pragma unroll
  for (int b = 0; b < BATCH; ++b) acc[b] = 0.f;
  const float* Wp = W + (size_t)k0 * DIM + c;
  const float* Ap = A + k0;
#pragma unroll 4
  for (int k = 0; k < KCH; ++k) {
    float wval = Wp[(size_t)k * DIM];
#pragma unroll
    for (int b = 0; b < BATCH; ++b)
      acc[b] += Ap[b * DIM + k] * wval;
  }
#pragma unroll
  for (int b = 0; b < BATCH; ++b)
    part[((size_t)sy * BATCH + b) * DIM + c] = acc[b];
}

__global__ __launch_bounds__(256) void wo_reduce(
    const float* __restrict__ part, float* __restrict__ out) {
  int idx = blockIdx.x * 256 + threadIdx.x;
  int b = idx >> 11, c2 = idx & 2047;
  int c = c2 * 2;
  float s0 = 0.f, s1 = 0.f;
#pragma unroll 8
  for (int s = 0; s < NSPLIT; ++s) {
    float2 pv = *(const float2*)&part[((size_t)s * BATCH + b) * DIM + c];
    s0 += pv.x; s1 += pv.y;
  }
  out[b * DIM + c]     = s0;
  out[b * DIM + c + 1] = s1;
}

extern "C" void kernel_launch(void* const* d_in, const int* in_sizes, int n_in,
                              void* d_out, int out_size, void* d_ws, size_t ws_size,
                              hipStream_t stream) {
  const float* x  = (const float*)d_in[0];
  const float* wq = (const float*)d_in[1];
  const float* wk = (const float*)d_in[2];
  const float* wv = (const float*)d_in[3];
  const float* wo = (const float*)d_in[4];
  const float* ck = (const float*)d_in[5];
  const float* cv = (const float*)d_in[6];
  const float* fc = (const float*)d_in[7];
  const float* fs = (const float*)d_in[8];
  float* out = (float*)d_out;

  float* ws    = (float*)d_ws;
  float* ws_q  = ws;               // 131072
  float* ws_k  = ws + 131072;      // 32768
  float* ws_v  = ws + 163840;      // 32768
  float* ws_a  = ws + 196608;      // 131072
  float* pm    = ws + 327680;      // 8192
  float* pl    = ws + 335872;      // 8192
  float* pacc  = ws + 344064;      // 1048576
  float* partq = ws + 1392640;     // 6291456
  float* parto = ws + 7684096;     // 4194304
  float* pm2   = ws + 11878400;    // 8192   (probe scratch)
  float* pl2   = ws + 11886592;    // 8192
  float* pacc2 = ws + 11894784;    // 1048576

  gemm_qkv_part<<<dim3(24, NSPLIT), 256, 0, stream>>>(x, wq, wk, wv, partq);
  qkv_reduce_rope<<<384, 256, 0, stream>>>(partq, fc, fs, ws_q, ws_k, ws_v);

  // TIMING PROBE: duplicate attn dispatch into scratch. attn_dur = total - 344us.
  attn_kernel<<<BATCH * NKV * NCH, 256, 0, stream>>>(ws_q, ck, cv, ws_k, ws_v, pm2, pl2, pacc2);

  attn_kernel<<<BATCH * NKV * NCH, 256, 0, stream>>>(ws_q, ck, cv, ws_k, ws_v, pm, pl, pacc);
  combine_kernel<<<512, 256, 0, stream>>>(pm, pl, pacc, ws_a);

  gemm_wo_part<<<dim3(16, NSPLIT), 256, 0, stream>>>(ws_a, wo, parto);
  wo_reduce<<<256, 256, 0, stream>>>(parto, out);
}

// Round 8
// 500.247 us; speedup vs baseline: 1.0492x; 1.0492x over previous
//
#include <hip/hip_runtime.h>

#define BATCH 32
#define DIM 4096
#define NH 32
#define NKV 8
#define HD 128
#define CTX 4096
#define NEWT 4095
#define CHUNK 512
#define NCH 8
#define NSPLIT 32
#define KCH (DIM / NSPLIT)   // 128
#define NQKV 6144            // 4096 q + 1024 k + 1024 v
#define SM_SCALE 0.08838834764831845f  // 1/sqrt(128)

// ---- stage 1: partial GEMM, no atomics ----
__global__ __launch_bounds__(256) void gemm_qkv_part(
    const float* __restrict__ A, const float* __restrict__ wq,
    const float* __restrict__ wk, const float* __restrict__ wv,
    float* __restrict__ part) {
  int bx = blockIdx.x;
  int sy = blockIdx.y;
  int cg = bx * 256 + threadIdx.x;
  const float* W; int cw, Nw;
  if (bx < 16)      { W = wq; cw = cg;        Nw = 4096; }
  else if (bx < 20) { W = wk; cw = cg - 4096; Nw = 1024; }
  else              { W = wv; cw = cg - 5120; Nw = 1024; }
  int k0 = sy * KCH;
  float acc[BATCH];
#pragma unroll
  for (int b = 0; b < BATCH; ++b) acc[b] = 0.f;
  const float* Wp = W + (size_t)k0 * Nw + cw;
  const float* Ap = A + k0;
#pragma unroll 4
  for (int k = 0; k < KCH; ++k) {
    float wval = Wp[(size_t)k * Nw];
#pragma unroll
    for (int b = 0; b < BATCH; ++b)
      acc[b] += Ap[b * DIM + k] * wval;
  }
#pragma unroll
  for (int b = 0; b < BATCH; ++b)
    part[((size_t)sy * BATCH + b) * NQKV + cg] = acc[b];
}

// ---- stage 2: reduce partials + RoPE ----
__global__ __launch_bounds__(256) void qkv_reduce_rope(
    const float* __restrict__ part, const float* __restrict__ cos_t,
    const float* __restrict__ sin_t, float* __restrict__ q,
    float* __restrict__ k, float* __restrict__ v) {
  int idx = blockIdx.x * 256 + threadIdx.x;
  int b = idx / 3072, c2 = idx - b * 3072;
  int c = c2 * 2;
  float s0 = 0.f, s1 = 0.f;
#pragma unroll 8
  for (int s = 0; s < NSPLIT; ++s) {
    float2 pv = *(const float2*)&part[((size_t)s * BATCH + b) * NQKV + c];
    s0 += pv.x; s1 += pv.y;
  }
  if (c < 4096) {
    int p = (c & 127) >> 1;
    float cc = cos_t[p], ss = sin_t[p];
    q[b * 4096 + c]     = s0 * cc - s1 * ss;
    q[b * 4096 + c + 1] = s0 * ss + s1 * cc;
  } else if (c < 5120) {
    int c0 = c - 4096;
    int p = (c0 & 127) >> 1;
    float cc = cos_t[p], ss = sin_t[p];
    k[b * 1024 + c0]     = s0 * cc - s1 * ss;
    k[b * 1024 + c0 + 1] = s0 * ss + s1 * cc;
  } else {
    int c0 = c - 5120;
    v[b * 1024 + c0]     = s0;
    v[b * 1024 + c0 + 1] = s1;
  }
}

// ---- flash-decode partial: one block per (b, kv_head, chunk) ----
__global__ __launch_bounds__(256, 2) void attn_kernel(
    const float* __restrict__ q,
    const float* __restrict__ kcache,
    const float* __restrict__ vcache,
    const float* __restrict__ knew,
    const float* __restrict__ vnew,
    float* __restrict__ pm, float* __restrict__ pl,
    float* __restrict__ pacc) {
  __shared__ float sc[4 * CHUNK];   // 8 KB
  __shared__ float sml[8];
  int blk = blockIdx.x;
  int c = blk & 7, h = (blk >> 3) & 7, b = blk >> 6;
  int tid = threadIdx.x;
  int wave = tid >> 6, sub = tid & 63;
  int t_base = c * CHUNK;

  // phase 1: scores
  int tg = tid >> 4;    // 0..15 t-rows per pass
  int lig = tid & 15;   // covers 8 d's
  float qreg[4][8];
#pragma unroll
  for (int r = 0; r < 4; ++r)
#pragma unroll
    for (int j = 0; j < 8; ++j)
      qreg[r][j] = q[b * (NH * HD) + (h * 4 + r) * HD + lig * 8 + j];

  const float* kbase = kcache + ((size_t)b * CTX * NKV + h) * HD;
  const float* knrow = knew + (b * NKV + h) * HD;
  for (int t0 = 0; t0 < CHUNK; t0 += 16) {
    int tl = t0 + tg;
    int t = t_base + tl;
    const float* krow = (t < NEWT) ? (kbase + (size_t)t * (NKV * HD)) : knrow;
    float4 ka = *(const float4*)(krow + lig * 8);
    float4 kb = *(const float4*)(krow + lig * 8 + 4);
#pragma unroll
    for (int r = 0; r < 4; ++r) {
      float part = ka.x * qreg[r][0] + ka.y * qreg[r][1] + ka.z * qreg[r][2] + ka.w * qreg[r][3]
                 + kb.x * qreg[r][4] + kb.y * qreg[r][5] + kb.z * qreg[r][6] + kb.w * qreg[r][7];
#pragma unroll
      for (int off = 8; off >= 1; off >>= 1)
        part += __shfl_xor(part, off);
      if (lig == 0) sc[r * CHUNK + tl] = part * SM_SCALE;
    }
  }
  __syncthreads();

  // chunk softmax (unnormalized), wave r handles row r
  {
    int r = wave;
    float m = -1e30f;
    for (int i = sub; i < CHUNK; i += 64) m = fmaxf(m, sc[r * CHUNK + i]);
#pragma unroll
    for (int off = 32; off >= 1; off >>= 1) m = fmaxf(m, __shfl_xor(m, off));
    float ssum = 0.f;
    for (int i = sub; i < CHUNK; i += 64) {
      float pv = __expf(sc[r * CHUNK + i] - m);
      sc[r * CHUNK + i] = pv;
      ssum += pv;
    }
#pragma unroll
    for (int off = 32; off >= 1; off >>= 1) ssum += __shfl_xor(ssum, off);
    if (sub == 0) { sml[r] = m; sml[4 + r] = ssum; }
  }
  __syncthreads();
  if (tid < 4) {
    pm[blk * 4 + tid] = sml[tid];
    pl[blk * 4 + tid] = sml[4 + tid];
  }

  // phase 2: acc[r][d] = sum_t p[r][t] * V[t][d]
  int dg = tid & 31;
  int tg2 = tid >> 5;   // 0..7
  float4 acc[4];
#pragma unroll
  for (int r = 0; r < 4; ++r) acc[r] = make_float4(0.f, 0.f, 0.f, 0.f);
  const float* vbase = vcache + ((size_t)b * CTX * NKV + h) * HD;
  const float* vnrow = vnew + (b * NKV + h) * HD;
  for (int t0 = 0; t0 < CHUNK; t0 += 16) {
    int tla = t0 + tg2, tlb = t0 + tg2 + 8;
    int ta = t_base + tla, tb = t_base + tlb;
    const float* vra = (ta < NEWT) ? (vbase + (size_t)ta * (NKV * HD)) : vnrow;
    const float* vrb = (tb < NEWT) ? (vbase + (size_t)tb * (NKV * HD)) : vnrow;
    float4 va = *(const float4*)(vra + dg * 4);
    float4 vb = *(const float4*)(vrb + dg * 4);
#pragma unroll
    for (int r = 0; r < 4; ++r) {
      float pa = sc[r * CHUNK + tla];
      float pb = sc[r * CHUNK + tlb];
      acc[r].x += pa * va.x + pb * vb.x;
      acc[r].y += pa * va.y + pb * vb.y;
      acc[r].z += pa * va.z + pb * vb.z;
      acc[r].w += pa * va.w + pb * vb.w;
    }
  }
#pragma unroll
  for (int r = 0; r < 4; ++r) {
    acc[r].x += __shfl_xor(acc[r].x, 32);
    acc[r].y += __shfl_xor(acc[r].y, 32);
    acc[r].z += __shfl_xor(acc[r].z, 32);
    acc[r].w += __shfl_xor(acc[r].w, 32);
  }
  __syncthreads();
  if (sub < 32) {
#pragma unroll
    for (int r = 0; r < 4; ++r)
      *(float4*)&sc[wave * 512 + r * 128 + dg * 4] = acc[r];
  }
  __syncthreads();
#pragma unroll
  for (int rr = 0; rr < 2; ++rr) {
    int idx = tid + rr * 256;
    int r = idx >> 7, d = idx & 127;
    float s = sc[r * 128 + d] + sc[512 + r * 128 + d]
            + sc[1024 + r * 128 + d] + sc[1536 + r * 128 + d];
    pacc[(size_t)blk * 512 + r * 128 + d] = s;
  }
}

__global__ __launch_bounds__(256) void combine_kernel(
    const float* __restrict__ pm, const float* __restrict__ pl,
    const float* __restrict__ pacc, float* __restrict__ outa) {
  int idx = blockIdx.x * 256 + threadIdx.x;
  int d = idx & 127, r = (idx >> 7) & 3, h = (idx >> 9) & 7, b = idx >> 12;
  int base = (b * 8 + h) * 8;
  float M = -1e30f;
#pragma unroll
  for (int c = 0; c < NCH; ++c) M = fmaxf(M, pm[(base + c) * 4 + r]);
  float num = 0.f, den = 0.f;
#pragma unroll
  for (int c = 0; c < NCH; ++c) {
    float w = __expf(pm[(base + c) * 4 + r] - M);
    den += w * pl[(base + c) * 4 + r];
    num += w * pacc[(size_t)(base + c) * 512 + r * 128 + d];
  }
  outa[b * (NH * HD) + (h * 4 + r) * HD + d] = num / den;
}

// ---- wo projection ----
__global__ __launch_bounds__(256) void gemm_wo_part(
    const float* __restrict__ A, const float* __restrict__ W,
    float* __restrict__ part) {
  int c = blockIdx.x * 256 + threadIdx.x;
  int sy = blockIdx.y;
  int k0 = sy * KCH;
  float acc[BATCH];
#pragma unroll
  for (int b = 0; b < BATCH; ++b) acc[b] = 0.f;
  const float* Wp = W + (size_t)k0 * DIM + c;
  const float* Ap = A + k0;
#pragma unroll 4
  for (int k = 0; k < KCH; ++k) {
    float wval = Wp[(size_t)k * DIM];
#pragma unroll
    for (int b = 0; b < BATCH; ++b)
      acc[b] += Ap[b * DIM + k] * wval;
  }
#pragma unroll
  for (int b = 0; b < BATCH; ++b)
    part[((size_t)sy * BATCH + b) * DIM + c] = acc[b];
}

__global__ __launch_bounds__(256) void wo_reduce(
    const float* __restrict__ part, float* __restrict__ out) {
  int idx = blockIdx.x * 256 + threadIdx.x;
  int b = idx >> 11, c2 = idx & 2047;
  int c = c2 * 2;
  float s0 = 0.f, s1 = 0.f;
#pragma unroll 8
  for (int s = 0; s < NSPLIT; ++s) {
    float2 pv = *(const float2*)&part[((size_t)s * BATCH + b) * DIM + c];
    s0 += pv.x; s1 += pv.y;
  }
  out[b * DIM + c]     = s0;
  out[b * DIM + c + 1] = s1;
}

extern "C" void kernel_launch(void* const* d_in, const int* in_sizes, int n_in,
                              void* d_out, int out_size, void* d_ws, size_t ws_size,
                              hipStream_t stream) {
  const float* x  = (const float*)d_in[0];
  const float* wq = (const float*)d_in[1];
  const float* wk = (const float*)d_in[2];
  const float* wv = (const float*)d_in[3];
  const float* wo = (const float*)d_in[4];
  const float* ck = (const float*)d_in[5];
  const float* cv = (const float*)d_in[6];
  const float* fc = (const float*)d_in[7];
  const float* fs = (const float*)d_in[8];
  float* out = (float*)d_out;

  float* ws    = (float*)d_ws;
  float* ws_q  = ws;               // 131072
  float* ws_k  = ws + 131072;      // 32768
  float* ws_v  = ws + 163840;      // 32768
  float* ws_a  = ws + 196608;      // 131072
  float* pm    = ws + 327680;      // 8192
  float* pl    = ws + 335872;      // 8192
  float* pacc  = ws + 344064;      // 1048576
  float* partq = ws + 1392640;     // 6291456
  float* parto = ws + 7684096;     // 4194304
  float* partq2 = ws + 11878400;   // 6291456 (probe scratch)
  float* ws_q2  = ws + 18169856;   // 131072
  float* ws_k2  = ws + 18300928;   // 32768
  float* ws_v2  = ws + 18333696;   // 32768
  // total ~18.4M floats ~= 73 MB

  // TIMING PROBE: two extra copies of the projection pair into scratch.
  // proj_pair_cost = (total - 344us) / 2.
  gemm_qkv_part<<<dim3(24, NSPLIT), 256, 0, stream>>>(x, wq, wk, wv, partq2);
  qkv_reduce_rope<<<384, 256, 0, stream>>>(partq2, fc, fs, ws_q2, ws_k2, ws_v2);
  gemm_qkv_part<<<dim3(24, NSPLIT), 256, 0, stream>>>(x, wq, wk, wv, partq2);
  qkv_reduce_rope<<<384, 256, 0, stream>>>(partq2, fc, fs, ws_q2, ws_k2, ws_v2);

  gemm_qkv_part<<<dim3(24, NSPLIT), 256, 0, stream>>>(x, wq, wk, wv, partq);
  qkv_reduce_rope<<<384, 256, 0, stream>>>(partq, fc, fs, ws_q, ws_k, ws_v);

  attn_kernel<<<BATCH * NKV * NCH, 256, 0, stream>>>(ws_q, ck, cv, ws_k, ws_v, pm, pl, pacc);
  combine_kernel<<<512, 256, 0, stream>>>(pm, pl, pacc, ws_a);

  gemm_wo_part<<<dim3(16, NSPLIT), 256, 0, stream>>>(ws_a, wo, parto);
  wo_reduce<<<256, 256, 0, stream>>>(parto, out);
}

// Round 9
// 302.044 us; speedup vs baseline: 1.7377x; 1.6562x over previous
//
#include <hip/hip_runtime.h>

#define BATCH 32
#define DIM 4096
#define NH 32
#define NKV 8
#define HD 128
#define CTX 4096
#define NEWT 4095
#define CHUNK 512
#define NCH 8
#define NSPLIT 32
#define KCH (DIM / NSPLIT)   // 128
#define NQKV 6144            // 4096 q + 1024 k + 1024 v
#define SM_SCALE 0.08838834764831845f  // 1/sqrt(128)

// ---- transpose (32, N) -> (N, 32) ----
__global__ __launch_bounds__(256) void transpose32(
    const float* __restrict__ src, float* __restrict__ dst, int N) {
  __shared__ float tile[32][33];
  int n0 = blockIdx.x * 32;
  int tn = threadIdx.x & 31;
  int tb = threadIdx.x >> 5;   // 0..7
#pragma unroll
  for (int bb = 0; bb < 4; ++bb) {
    int b = bb * 8 + tb;
    tile[b][tn] = src[(size_t)b * N + n0 + tn];
  }
  __syncthreads();
  int wb = threadIdx.x & 31;
  int wn = threadIdx.x >> 5;   // 0..7
#pragma unroll
  for (int nn = 0; nn < 4; ++nn) {
    int n = nn * 8 + wn;
    dst[(size_t)(n0 + n) * 32 + wb] = tile[wb][n];
  }
}

// ---- stage 1: partial GEMM, A transposed (AT[k][b] contiguous) ----
__global__ __launch_bounds__(256) void gemm_qkv_part(
    const float* __restrict__ AT, const float* __restrict__ wq,
    const float* __restrict__ wk, const float* __restrict__ wv,
    float* __restrict__ part) {
  int bx = blockIdx.x;
  int sy = blockIdx.y;
  int cg = bx * 256 + threadIdx.x;
  const float* W; int cw, Nw;
  if (bx < 16)      { W = wq; cw = cg;        Nw = 4096; }
  else if (bx < 20) { W = wk; cw = cg - 4096; Nw = 1024; }
  else              { W = wv; cw = cg - 5120; Nw = 1024; }
  int k0 = sy * KCH;
  float acc[BATCH];
#pragma unroll
  for (int b = 0; b < BATCH; ++b) acc[b] = 0.f;
  const float* Wp = W + (size_t)k0 * Nw + cw;
  const float* ATp = AT + (size_t)k0 * 32;
#pragma unroll 2
  for (int k = 0; k < KCH; ++k) {
    float wval = Wp[(size_t)k * Nw];
    const float4* Ak = (const float4*)(ATp + k * 32);   // uniform, contiguous
#pragma unroll
    for (int q8 = 0; q8 < 8; ++q8) {
      float4 av = Ak[q8];
      acc[q8 * 4 + 0] += av.x * wval;
      acc[q8 * 4 + 1] += av.y * wval;
      acc[q8 * 4 + 2] += av.z * wval;
      acc[q8 * 4 + 3] += av.w * wval;
    }
  }
#pragma unroll
  for (int b = 0; b < BATCH; ++b)
    part[((size_t)sy * BATCH + b) * NQKV + cg] = acc[b];
}

// ---- stage 2: reduce partials + RoPE ----
__global__ __launch_bounds__(256) void qkv_reduce_rope(
    const float* __restrict__ part, const float* __restrict__ cos_t,
    const float* __restrict__ sin_t, float* __restrict__ q,
    float* __restrict__ k, float* __restrict__ v) {
  int idx = blockIdx.x * 256 + threadIdx.x;
  int b = idx / 3072, c2 = idx - b * 3072;
  int c = c2 * 2;
  float s0 = 0.f, s1 = 0.f;
#pragma unroll 8
  for (int s = 0; s < NSPLIT; ++s) {
    float2 pv = *(const float2*)&part[((size_t)s * BATCH + b) * NQKV + c];
    s0 += pv.x; s1 += pv.y;
  }
  if (c < 4096) {
    int p = (c & 127) >> 1;
    float cc = cos_t[p], ss = sin_t[p];
    q[b * 4096 + c]     = s0 * cc - s1 * ss;
    q[b * 4096 + c + 1] = s0 * ss + s1 * cc;
  } else if (c < 5120) {
    int c0 = c - 4096;
    int p = (c0 & 127) >> 1;
    float cc = cos_t[p], ss = sin_t[p];
    k[b * 1024 + c0]     = s0 * cc - s1 * ss;
    k[b * 1024 + c0 + 1] = s0 * ss + s1 * cc;
  } else {
    int c0 = c - 5120;
    v[b * 1024 + c0]     = s0;
    v[b * 1024 + c0 + 1] = s1;
  }
}

// ---- flash-decode partial: one block per (b, kv_head, chunk) ----
__global__ __launch_bounds__(256, 2) void attn_kernel(
    const float* __restrict__ q,
    const float* __restrict__ kcache,
    const float* __restrict__ vcache,
    const float* __restrict__ knew,
    const float* __restrict__ vnew,
    float* __restrict__ pm, float* __restrict__ pl,
    float* __restrict__ pacc) {
  __shared__ float sc[4 * CHUNK];   // 8 KB
  __shared__ float sml[8];
  int blk = blockIdx.x;
  int c = blk & 7, h = (blk >> 3) & 7, b = blk >> 6;
  int tid = threadIdx.x;
  int wave = tid >> 6, sub = tid & 63;
  int t_base = c * CHUNK;

  // phase 1: scores
  int tg = tid >> 4;    // 0..15 t-rows per pass
  int lig = tid & 15;   // covers 8 d's
  float qreg[4][8];
#pragma unroll
  for (int r = 0; r < 4; ++r)
#pragma unroll
    for (int j = 0; j < 8; ++j)
      qreg[r][j] = q[b * (NH * HD) + (h * 4 + r) * HD + lig * 8 + j];

  const float* kbase = kcache + ((size_t)b * CTX * NKV + h) * HD;
  const float* knrow = knew + (b * NKV + h) * HD;
  for (int t0 = 0; t0 < CHUNK; t0 += 16) {
    int tl = t0 + tg;
    int t = t_base + tl;
    const float* krow = (t < NEWT) ? (kbase + (size_t)t * (NKV * HD)) : knrow;
    float4 ka = *(const float4*)(krow + lig * 8);
    float4 kb = *(const float4*)(krow + lig * 8 + 4);
#pragma unroll
    for (int r = 0; r < 4; ++r) {
      float part = ka.x * qreg[r][0] + ka.y * qreg[r][1] + ka.z * qreg[r][2] + ka.w * qreg[r][3]
                 + kb.x * qreg[r][4] + kb.y * qreg[r][5] + kb.z * qreg[r][6] + kb.w * qreg[r][7];
#pragma unroll
      for (int off = 8; off >= 1; off >>= 1)
        part += __shfl_xor(part, off);
      if (lig == 0) sc[r * CHUNK + tl] = part * SM_SCALE;
    }
  }
  __syncthreads();

  // chunk softmax (unnormalized), wave r handles row r
  {
    int r = wave;
    float m = -1e30f;
    for (int i = sub; i < CHUNK; i += 64) m = fmaxf(m, sc[r * CHUNK + i]);
#pragma unroll
    for (int off = 32; off >= 1; off >>= 1) m = fmaxf(m, __shfl_xor(m, off));
    float ssum = 0.f;
    for (int i = sub; i < CHUNK; i += 64) {
      float pv = __expf(sc[r * CHUNK + i] - m);
      sc[r * CHUNK + i] = pv;
      ssum += pv;
    }
#pragma unroll
    for (int off = 32; off >= 1; off >>= 1) ssum += __shfl_xor(ssum, off);
    if (sub == 0) { sml[r] = m; sml[4 + r] = ssum; }
  }
  __syncthreads();
  if (tid < 4) {
    pm[blk * 4 + tid] = sml[tid];
    pl[blk * 4 + tid] = sml[4 + tid];
  }

  // phase 2: acc[r][d] = sum_t p[r][t] * V[t][d]
  int dg = tid & 31;
  int tg2 = tid >> 5;   // 0..7
  float4 acc[4];
#pragma unroll
  for (int r = 0; r < 4; ++r) acc[r] = make_float4(0.f, 0.f, 0.f, 0.f);
  const float* vbase = vcache + ((size_t)b * CTX * NKV + h) * HD;
  const float* vnrow = vnew + (b * NKV + h) * HD;
  for (int t0 = 0; t0 < CHUNK; t0 += 16) {
    int tla = t0 + tg2, tlb = t0 + tg2 + 8;
    int ta = t_base + tla, tb = t_base + tlb;
    const float* vra = (ta < NEWT) ? (vbase + (size_t)ta * (NKV * HD)) : vnrow;
    const float* vrb = (tb < NEWT) ? (vbase + (size_t)tb * (NKV * HD)) : vnrow;
    float4 va = *(const float4*)(vra + dg * 4);
    float4 vb = *(const float4*)(vrb + dg * 4);
#pragma unroll
    for (int r = 0; r < 4; ++r) {
      float pa = sc[r * CHUNK + tla];
      float pb = sc[r * CHUNK + tlb];
      acc[r].x += pa * va.x + pb * vb.x;
      acc[r].y += pa * va.y + pb * vb.y;
      acc[r].z += pa * va.z + pb * vb.z;
      acc[r].w += pa * va.w + pb * vb.w;
    }
  }
#pragma unroll
  for (int r = 0; r < 4; ++r) {
    acc[r].x += __shfl_xor(acc[r].x, 32);
    acc[r].y += __shfl_xor(acc[r].y, 32);
    acc[r].z += __shfl_xor(acc[r].z, 32);
    acc[r].w += __shfl_xor(acc[r].w, 32);
  }
  __syncthreads();
  if (sub < 32) {
#pragma unroll
    for (int r = 0; r < 4; ++r)
      *(float4*)&sc[wave * 512 + r * 128 + dg * 4] = acc[r];
  }
  __syncthreads();
#pragma unroll
  for (int rr = 0; rr < 2; ++rr) {
    int idx = tid + rr * 256;
    int r = idx >> 7, d = idx & 127;
    float s = sc[r * 128 + d] + sc[512 + r * 128 + d]
            + sc[1024 + r * 128 + d] + sc[1536 + r * 128 + d];
    pacc[(size_t)blk * 512 + r * 128 + d] = s;
  }
}

__global__ __launch_bounds__(256) void combine_kernel(
    const float* __restrict__ pm, const float* __restrict__ pl,
    const float* __restrict__ pacc, float* __restrict__ outa) {
  int idx = blockIdx.x * 256 + threadIdx.x;
  int d = idx & 127, r = (idx >> 7) & 3, h = (idx >> 9) & 7, b = idx >> 12;
  int base = (b * 8 + h) * 8;
  float M = -1e30f;
#pragma unroll
  for (int c = 0; c < NCH; ++c) M = fmaxf(M, pm[(base + c) * 4 + r]);
  float num = 0.f, den = 0.f;
#pragma unroll
  for (int c = 0; c < NCH; ++c) {
    float w = __expf(pm[(base + c) * 4 + r] - M);
    den += w * pl[(base + c) * 4 + r];
    num += w * pacc[(size_t)(base + c) * 512 + r * 128 + d];
  }
  outa[b * (NH * HD) + (h * 4 + r) * HD + d] = num / den;
}

// ---- wo projection, A transposed ----
__global__ __launch_bounds__(256) void gemm_wo_part(
    const float* __restrict__ AT, const float* __restrict__ W,
    float* __restrict__ part) {
  int c = blockIdx.x * 256 + threadIdx.x;
  int sy = blockIdx.y;
  int k0 = sy * KCH;
  float acc[BATCH];
#pragma unroll
  for (int b = 0; b < BATCH; ++b) acc[b] = 0.f;
  const float* Wp = W + (size_t)k0 * DIM + c;
  const float* ATp = AT + (size_t)k0 * 32;
#pragma unroll 2
  for (int k = 0; k < KCH; ++k) {
    float wval = Wp[(size_t)k * DIM];
    const float4* Ak = (const float4*)(ATp + k * 32);
#pragma unroll
    for (int q8 = 0; q8 < 8; ++q8) {
      float4 av = Ak[q8];
      acc[q8 * 4 + 0] += av.x * wval;
      acc[q8 * 4 + 1] += av.y * wval;
      acc[q8 * 4 + 2] += av.z * wval;
      acc[q8 * 4 + 3] += av.w * wval;
    }
  }
#pragma unroll
  for (int b = 0; b < BATCH; ++b)
    part[((size_t)sy * BATCH + b) * DIM + c] = acc[b];
}

__global__ __launch_bounds__(256) void wo_reduce(
    const float* __restrict__ part, float* __restrict__ out) {
  int idx = blockIdx.x * 256 + threadIdx.x;
  int b = idx >> 11, c2 = idx & 2047;
  int c = c2 * 2;
  float s0 = 0.f, s1 = 0.f;
#pragma unroll 8
  for (int s = 0; s < NSPLIT; ++s) {
    float2 pv = *(const float2*)&part[((size_t)s * BATCH + b) * DIM + c];
    s0 += pv.x; s1 += pv.y;
  }
  out[b * DIM + c]     = s0;
  out[b * DIM + c + 1] = s1;
}

extern "C" void kernel_launch(void* const* d_in, const int* in_sizes, int n_in,
                              void* d_out, int out_size, void* d_ws, size_t ws_size,
                              hipStream_t stream) {
  const float* x  = (const float*)d_in[0];
  const float* wq = (const float*)d_in[1];
  const float* wk = (const float*)d_in[2];
  const float* wv = (const float*)d_in[3];
  const float* wo = (const float*)d_in[4];
  const float* ck = (const float*)d_in[5];
  const float* cv = (const float*)d_in[6];
  const float* fc = (const float*)d_in[7];
  const float* fs = (const float*)d_in[8];
  float* out = (float*)d_out;

  float* ws    = (float*)d_ws;
  float* ws_q  = ws;               // 131072
  float* ws_k  = ws + 131072;      // 32768
  float* ws_v  = ws + 163840;      // 32768
  float* ws_a  = ws + 196608;      // 131072
  float* pm    = ws + 327680;      // 8192
  float* pl    = ws + 335872;      // 8192
  float* pacc  = ws + 344064;      // 1048576
  float* partq = ws + 1392640;     // 6291456
  float* parto = ws + 7684096;     // 4194304
  float* xT    = ws + 11878400;    // 131072
  float* aT    = ws + 12009472;    // 131072
  // total ~12.1M floats ~= 48.6 MB

  transpose32<<<128, 256, 0, stream>>>(x, xT, DIM);
  gemm_qkv_part<<<dim3(24, NSPLIT), 256, 0, stream>>>(xT, wq, wk, wv, partq);
  qkv_reduce_rope<<<384, 256, 0, stream>>>(partq, fc, fs, ws_q, ws_k, ws_v);

  attn_kernel<<<BATCH * NKV * NCH, 256, 0, stream>>>(ws_q, ck, cv, ws_k, ws_v, pm, pl, pacc);
  combine_kernel<<<512, 256, 0, stream>>>(pm, pl, pacc, ws_a);

  transpose32<<<128, 256, 0, stream>>>(ws_a, aT, DIM);
  gemm_wo_part<<<dim3(16, NSPLIT), 256, 0, stream>>>(aT, wo, parto);
  wo_reduce<<<256, 256, 0, stream>>>(parto, out);
}